// Round 3
// baseline (515.792 us; speedup 1.0000x reference)
//
#include <hip/hip_runtime.h>
#include <hip/hip_bf16.h>

typedef __attribute__((ext_vector_type(4))) float  f32x4;
typedef __attribute__((ext_vector_type(8))) short  bf16x8;
typedef __attribute__((ext_vector_type(4))) short  bf16x4;

#define MFMA16(a, b, c) __builtin_amdgcn_mfma_f32_16x16x32_bf16((a), (b), (c), 0, 0, 0)

__device__ __forceinline__ short f2bf(float f) {
  return __builtin_bit_cast(short, __float2bfloat16(f));
}
__device__ __forceinline__ float bf2f(short b) {
  return __builtin_bit_cast(float, ((unsigned)(unsigned short)b) << 16);
}

constexpr int L = 2048, D = 64, KT = 64, NT = L / KT;   // 32 k-tiles
constexpr int QB = 128, NQT = L / QB;                    // 128 q-rows/block, 16 q-tiles
constexpr int NHEAD = 64;
// softmax in exp2 domain: exp(s/T) = exp2(s * 0.125*log2(e))
constexpr float QSCALE = 0.18033688011112042f;

__global__ __launch_bounds__(256, 4)
void sdpa_fused(const float* __restrict__ Q, const float* __restrict__ K,
                const float* __restrict__ V, float* __restrict__ out,
                float* __restrict__ attn)
{
  __shared__ short Klds[2][KT * D];     // [buf][kr][d] bf16, row-XOR-swizzled
  __shared__ short Vlds[2][D * KT];     // [buf][d][kr] bf16 (V^T), row-XOR-swizzled
  __shared__ short Plds[4][16 * KT];    // per-wave, one 16-q half at a time

  const int t    = threadIdx.x;
  const int lane = t & 63;
  const int w    = t >> 6;
  const int qr   = lane & 15;
  const int g    = lane >> 4;

  // XCD-aware swizzle: 1024 blocks, 8 XCDs -> all 16 blocks of a head on one XCD
  const int bid  = blockIdx.x;
  const int wid  = ((bid & 7) << 7) | (bid >> 3);
  const int head = wid >> 4;
  const int qt   = wid & 15;
  const long hoff = (long)head * L * D;
  const int qrow0 = qt * QB + w * 32;   // this wave's 32-row q-strip

  // ---- Q fragments (B-operand of S^T = K*Q^T), scale folded. h = q-half ----
  bf16x8 qfrag[2][2];
  #pragma unroll
  for (int h = 0; h < 2; ++h) {
    const float* qp = Q + hoff + (long)(qrow0 + 16 * h + qr) * D + g * 8;
    #pragma unroll
    for (int c = 0; c < 2; ++c)
      #pragma unroll
      for (int j = 0; j < 8; ++j)
        qfrag[h][c][j] = f2bf(qp[32 * c + j] * QSCALE);
  }

  const float* Kbase = K + hoff;
  const float* Vbase = V + hoff;

  f32x4 kreg[4], vreg[4];   // async-split staging: load early, LDS-write late

  auto loadK = [&](int kt) {
    const float* kp = Kbase + (long)kt * KT * D;
    #pragma unroll
    for (int c = 0; c < 4; ++c)
      kreg[c] = *(const f32x4*)(kp + (t + 256 * c) * 4);
  };
  auto writeK = [&](int buf) {
    #pragma unroll
    for (int c = 0; c < 4; ++c) {
      int f = t + 256 * c;
      int kr = f >> 4, col = (f & 15) * 4;
      bf16x4 y;
      #pragma unroll
      for (int i = 0; i < 4; ++i) y[i] = f2bf(kreg[c][i]);
      *(bf16x4*)(&Klds[buf][kr * 64 + (col ^ ((kr & 7) << 3))]) = y;
    }
  };
  auto loadV = [&](int kt) {
    const float* vp = Vbase + (long)kt * KT * D;
    int kr0 = (t >> 4) * 4, d0 = (t & 15) * 4;
    #pragma unroll
    for (int i = 0; i < 4; ++i)
      vreg[i] = *(const f32x4*)(vp + (kr0 + i) * D + d0);
  };
  auto writeV = [&](int buf) {  // in-register 4x4 transpose
    int kr0 = (t >> 4) * 4, d0 = (t & 15) * 4;
    #pragma unroll
    for (int j = 0; j < 4; ++j) {
      bf16x4 y;
      #pragma unroll
      for (int i = 0; i < 4; ++i) y[i] = f2bf(vreg[i][j]);
      int d = d0 + j;
      *(bf16x4*)(&Vlds[buf][d * 64 + (kr0 ^ ((d & 7) << 3))]) = y;
    }
  };

  auto computeS = [&](int buf, int h, f32x4 s[4]) {
    #pragma unroll
    for (int f = 0; f < 4; ++f) {
      s[f] = (f32x4){0.f, 0.f, 0.f, 0.f};
      int kr = f * 16 + qr;
      #pragma unroll
      for (int c = 0; c < 2; ++c) {
        int d0c = g * 8 + 32 * c;
        bf16x8 a = *(const bf16x8*)(&Klds[buf][kr * 64 + (d0c ^ ((kr & 7) << 3))]);
        s[f] = MFMA16(a, qfrag[h][c], s[f]);
      }
    }
  };

  // ================= pass 1: row sums =================
  loadK(0); writeK(0);
  __syncthreads();
  float rsum[2] = {0.f, 0.f};
  for (int kt = 0; kt < NT; ++kt) {
    const int cur = kt & 1;
    if (kt + 1 < NT) loadK(kt + 1);
    #pragma unroll
    for (int h = 0; h < 2; ++h) {
      f32x4 s[4];
      computeS(cur, h, s);
      #pragma unroll
      for (int f = 0; f < 4; ++f)
        #pragma unroll
        for (int r = 0; r < 4; ++r)
          rsum[h] += __builtin_amdgcn_exp2f(s[f][r]);
    }
    if (kt + 1 < NT) writeK(cur ^ 1);
    __syncthreads();
  }
  float rinv[2];
  #pragma unroll
  for (int h = 0; h < 2; ++h) {
    rsum[h] += __shfl_xor(rsum[h], 16);
    rsum[h] += __shfl_xor(rsum[h], 32);
    rinv[h] = 1.f / rsum[h];
  }

  // ================= pass 2: attn + O =================
  f32x4 o[2][4];
  #pragma unroll
  for (int h = 0; h < 2; ++h)
    #pragma unroll
    for (int fr = 0; fr < 4; ++fr)
      o[h][fr] = (f32x4){0.f, 0.f, 0.f, 0.f};

  float* ap_base = attn + (long)head * L * L + (long)qrow0 * L;

  loadK(0); loadV(0);
  writeK(0); writeV(0);
  __syncthreads();

  for (int kt = 0; kt < NT; ++kt) {
    const int cur = kt & 1;
    if (kt + 1 < NT) { loadK(kt + 1); loadV(kt + 1); }

    #pragma unroll
    for (int h = 0; h < 2; ++h) {
      f32x4 s[4];
      computeS(cur, h, s);

      // P-half = exp2(s)*rinv -> bf16 -> wave-private Plds (16 q-rows)
      __builtin_amdgcn_wave_barrier();           // keep halves ordered
      #pragma unroll
      for (int f = 0; f < 4; ++f) {
        bf16x4 p;
        #pragma unroll
        for (int r = 0; r < 4; ++r)
          p[r] = f2bf(__builtin_amdgcn_exp2f(s[f][r]) * rinv[h]);
        int k0 = f * 16 + g * 4;
        *(bf16x4*)(&Plds[w][qr * 64 + (k0 ^ ((qr & 7) << 3))]) = p;
      }
      __builtin_amdgcn_wave_barrier();

      // attn write: quarter-wave writes contiguous 256B row segments
      float* ap = ap_base + (long)(16 * h) * L + (long)kt * KT;
      #pragma unroll
      for (int i = 0; i < 4; ++i) {
        int r = 4 * i + g, col = 4 * qr;
        bf16x4 pb = *(const bf16x4*)(&Plds[w][r * 64 + (col ^ ((r & 7) << 3))]);
        f32x4 pf;
        #pragma unroll
        for (int j = 0; j < 4; ++j) pf[j] = bf2f(pb[j]);
        *(f32x4*)(ap + (long)r * L + col) = pf;
      }

      // PV: O-half(16q x 64d) += P(16x64) * V(64x64)
      #pragma unroll
      for (int kc = 0; kc < 2; ++kc) {
        int k0 = kc * 32 + g * 8;
        bf16x8 pa = *(const bf16x8*)(&Plds[w][qr * 64 + (k0 ^ ((qr & 7) << 3))]);
        #pragma unroll
        for (int fr = 0; fr < 4; ++fr) {
          int d = fr * 16 + qr;
          bf16x8 vb = *(const bf16x8*)(&Vlds[cur][d * 64 + (k0 ^ ((d & 7) << 3))]);
          o[h][fr] = MFMA16(pa, vb, o[h][fr]);
        }
      }
    }

    if (kt + 1 < NT) { writeK(cur ^ 1); writeV(cur ^ 1); }
    __syncthreads();
  }

  // ---- O writeback ----
  float* op = out + hoff + (long)qrow0 * D;
  #pragma unroll
  for (int h = 0; h < 2; ++h)
    #pragma unroll
    for (int fr = 0; fr < 4; ++fr)
      #pragma unroll
      for (int r = 0; r < 4; ++r) {
        int qq = 16 * h + g * 4 + r;
        op[(long)qq * D + fr * 16 + qr] = o[h][fr][r];
      }
}

extern "C" void kernel_launch(void* const* d_in, const int* in_sizes, int n_in,
                              void* d_out, int out_size, void* d_ws, size_t ws_size,
                              hipStream_t stream) {
  const float* q = (const float*)d_in[0];
  const float* k = (const float*)d_in[1];
  const float* v = (const float*)d_in[2];
  float* out  = (float*)d_out;                          // (B,H,L,D)
  float* attn = (float*)d_out + (size_t)NHEAD * L * D;  // (B,H,L,L)
  dim3 grid(NHEAD * NQT);   // 1024
  dim3 block(256);
  hipLaunchKernelGGL(sdpa_fused, grid, block, 0, stream, q, k, v, out, attn);
}

// Round 5
// 416.045 us; speedup vs baseline: 1.2397x; 1.2397x over previous
//
#include <hip/hip_runtime.h>
#include <hip/hip_bf16.h>

typedef __attribute__((ext_vector_type(4))) float  f32x4;
typedef __attribute__((ext_vector_type(8))) short  bf16x8;
typedef __attribute__((ext_vector_type(4))) short  bf16x4;

#define MFMA16(a, b, c) __builtin_amdgcn_mfma_f32_16x16x32_bf16((a), (b), (c), 0, 0, 0)

__device__ __forceinline__ short f2bf(float f) {
  return __builtin_bit_cast(short, __float2bfloat16(f));
}
__device__ __forceinline__ float bf2f(short b) {
  return __builtin_bit_cast(float, ((unsigned)(unsigned short)b) << 16);
}

// LDS-only barrier: drain ds ops (lgkmcnt) but let global stores/loads stay
// in flight across the barrier (no vmcnt(0) drain like __syncthreads emits).
// Safe here: no cross-wave communication through global memory exists in this
// kernel (attn stores are write-only; kreg/vreg prefetch regs are private and
// the compiler inserts vmcnt waits for their true data deps).
__device__ __forceinline__ void sync_lds() {
  asm volatile("s_waitcnt lgkmcnt(0)" ::: "memory");
  __builtin_amdgcn_s_barrier();
  asm volatile("" ::: "memory");
}

constexpr int L = 2048, D = 64, KT = 64, NT = L / KT;   // 32 k-tiles
constexpr int NHEAD = 64;                                // B*H
// softmax in exp2 domain: exp(s/T) = exp2(s * 0.125*log2(e))
constexpr float QSCALE = 0.18033688011112042f;

__global__ __launch_bounds__(256, 4)
void sdpa_fused(const float* __restrict__ Q, const float* __restrict__ K,
                const float* __restrict__ V, float* __restrict__ out,
                float* __restrict__ attn)
{
  __shared__ short Klds[2][KT * D];     // [buf][kr][d] bf16, row-XOR-swizzled
  __shared__ short Vlds[2][D * KT];     // [buf][d][kr] bf16 (V^T), row-XOR-swizzled
  __shared__ short Plds[4][16 * KT];    // per-wave [q][k] bf16 (wave-private)

  const int t    = threadIdx.x;
  const int lane = t & 63;
  const int w    = t >> 6;
  const int qr   = lane & 15;
  const int g    = lane >> 4;

  const int head  = blockIdx.x >> 5;
  const int qt    = blockIdx.x & 31;
  const long hoff = (long)head * L * D;
  const int qrow0 = qt * 64 + w * 16;

  // ---- Q fragments (B-operand of S^T = K*Q^T), scale folded ----
  bf16x8 qfrag[2];
  {
    const float* qp = Q + hoff + (long)(qrow0 + qr) * D + g * 8;
    #pragma unroll
    for (int c = 0; c < 2; ++c)
      #pragma unroll
      for (int j = 0; j < 8; ++j)
        qfrag[c][j] = f2bf(qp[32 * c + j] * QSCALE);
  }

  const float* Kbase = K + hoff;
  const float* Vbase = V + hoff;

  // staged-in-register tiles (async-split: load early, write-LDS late)
  f32x4 kreg[4], vreg[4];

  auto loadK = [&](int kt) {
    const float* kp = Kbase + (long)kt * KT * D;
    #pragma unroll
    for (int c = 0; c < 4; ++c)
      kreg[c] = *(const f32x4*)(kp + (t + 256 * c) * 4);   // fully coalesced
  };
  auto writeK = [&](int buf) {
    #pragma unroll
    for (int c = 0; c < 4; ++c) {
      int f = t + 256 * c;
      int kr = f >> 4, col = (f & 15) * 4;
      bf16x4 y;
      #pragma unroll
      for (int i = 0; i < 4; ++i) y[i] = f2bf(kreg[c][i]);
      *(bf16x4*)(&Klds[buf][kr * 64 + (col ^ ((kr & 7) << 3))]) = y;
    }
  };
  auto loadV = [&](int kt) {   // thread owns a 4(kr) x 4(d) block; rows coalesced
    const float* vp = Vbase + (long)kt * KT * D;
    int kr0 = (t >> 4) * 4, d0 = (t & 15) * 4;
    #pragma unroll
    for (int i = 0; i < 4; ++i)
      vreg[i] = *(const f32x4*)(vp + (kr0 + i) * D + d0);
  };
  auto writeV = [&](int buf) {  // in-register 4x4 transpose -> vectorized b64 writes
    int kr0 = (t >> 4) * 4, d0 = (t & 15) * 4;
    #pragma unroll
    for (int j = 0; j < 4; ++j) {
      bf16x4 y;
      #pragma unroll
      for (int i = 0; i < 4; ++i) y[i] = f2bf(vreg[i][j]);
      int d = d0 + j;
      *(bf16x4*)(&Vlds[buf][d * 64 + (kr0 ^ ((d & 7) << 3))]) = y;
    }
  };

  auto computeS = [&](int buf, f32x4 s[4]) {
    #pragma unroll
    for (int f = 0; f < 4; ++f) {
      s[f] = (f32x4){0.f, 0.f, 0.f, 0.f};
      int kr = f * 16 + qr;
      #pragma unroll
      for (int c = 0; c < 2; ++c) {
        int d0c = g * 8 + 32 * c;
        bf16x8 a = *(const bf16x8*)(&Klds[buf][kr * 64 + (d0c ^ ((kr & 7) << 3))]);
        s[f] = MFMA16(a, qfrag[c], s[f]);
      }
    }
  };

  // ================= pass 1: row sums (K only, double-buffered) =================
  loadK(0); writeK(0);
  sync_lds();
  float rsum = 0.f;
  for (int kt = 0; kt < NT; ++kt) {
    const int cur = kt & 1;
    if (kt + 1 < NT) loadK(kt + 1);        // prefetch next tile into regs
    f32x4 s[4];
    computeS(cur, s);
    #pragma unroll
    for (int f = 0; f < 4; ++f)
      #pragma unroll
      for (int r = 0; r < 4; ++r)
        rsum += __builtin_amdgcn_exp2f(s[f][r]);
    if (kt + 1 < NT) writeK(cur ^ 1);      // convert + stage into other buffer
    sync_lds();                             // single LDS-only barrier per tile
  }
  rsum += __shfl_xor(rsum, 16);
  rsum += __shfl_xor(rsum, 32);
  const float rinv = 1.f / rsum;

  // ================= pass 2: attn + O =================
  f32x4 o[4] = {{0.f,0.f,0.f,0.f},{0.f,0.f,0.f,0.f},{0.f,0.f,0.f,0.f},{0.f,0.f,0.f,0.f}};
  float* ap_base = attn + (long)head * L * L + (long)qrow0 * L;

  loadK(0); loadV(0);
  writeK(0); writeV(0);
  sync_lds();

  for (int kt = 0; kt < NT; ++kt) {
    const int cur = kt & 1;
    if (kt + 1 < NT) { loadK(kt + 1); loadV(kt + 1); }   // prefetch into regs

    f32x4 s[4];
    computeS(cur, s);

    // P = exp2(s)*rinv -> bf16 -> wave-private Plds (no block barrier needed)
    #pragma unroll
    for (int f = 0; f < 4; ++f) {
      bf16x4 p;
      #pragma unroll
      for (int r = 0; r < 4; ++r)
        p[r] = f2bf(__builtin_amdgcn_exp2f(s[f][r]) * rinv);
      int k0 = f * 16 + g * 4;
      *(bf16x4*)(&Plds[w][qr * 64 + (k0 ^ ((qr & 7) << 3))]) = p;
    }
    __builtin_amdgcn_wave_barrier();   // ordering fence only (wave-private LDS)

    // attn write: each quarter-wave emits one contiguous 256B row segment
    float* ap = ap_base + (long)kt * KT;
    #pragma unroll
    for (int i = 0; i < 4; ++i) {
      int r = 4 * i + g, col = 4 * qr;
      bf16x4 pb = *(const bf16x4*)(&Plds[w][r * 64 + (col ^ ((r & 7) << 3))]);
      f32x4 pf;
      #pragma unroll
      for (int j = 0; j < 4; ++j) pf[j] = bf2f(pb[j]);
      *(f32x4*)(ap + (long)r * L + col) = pf;
    }

    // PV: O(16q x 64d) += P(16x64) * V(64x64)
    #pragma unroll
    for (int kc = 0; kc < 2; ++kc) {
      int k0 = kc * 32 + g * 8;
      bf16x8 pa = *(const bf16x8*)(&Plds[w][qr * 64 + (k0 ^ ((qr & 7) << 3))]);
      #pragma unroll
      for (int fr = 0; fr < 4; ++fr) {
        int d = fr * 16 + qr;
        bf16x8 vb = *(const bf16x8*)(&Vlds[cur][d * 64 + (k0 ^ ((d & 7) << 3))]);
        o[fr] = MFMA16(pa, vb, o[fr]);
      }
    }

    if (kt + 1 < NT) { writeK(cur ^ 1); writeV(cur ^ 1); }
    sync_lds();                             // single LDS-only barrier per tile
  }

  // ---- O writeback ----
  float* op = out + hoff + (long)qrow0 * D;
  #pragma unroll
  for (int fr = 0; fr < 4; ++fr)
    #pragma unroll
    for (int r = 0; r < 4; ++r) {
      int qq = g * 4 + r;
      op[(long)qq * D + fr * 16 + qr] = o[fr][r];
    }
}

extern "C" void kernel_launch(void* const* d_in, const int* in_sizes, int n_in,
                              void* d_out, int out_size, void* d_ws, size_t ws_size,
                              hipStream_t stream) {
  const float* q = (const float*)d_in[0];
  const float* k = (const float*)d_in[1];
  const float* v = (const float*)d_in[2];
  float* out  = (float*)d_out;                          // (B,H,L,D)
  float* attn = (float*)d_out + (size_t)NHEAD * L * D;  // (B,H,L,L)
  dim3 grid(NHEAD * (L / 64));   // 2048
  dim3 block(256);
  hipLaunchKernelGGL(sdpa_fused, grid, block, 0, stream, q, k, v, out, attn);
}

// Round 6
// 387.173 us; speedup vs baseline: 1.3322x; 1.0746x over previous
//
#include <hip/hip_runtime.h>
#include <hip/hip_bf16.h>

typedef __attribute__((ext_vector_type(4))) float  f32x4;
typedef __attribute__((ext_vector_type(8))) short  bf16x8;
typedef __attribute__((ext_vector_type(4))) short  bf16x4;

#define MFMA16(a, b, c) __builtin_amdgcn_mfma_f32_16x16x32_bf16((a), (b), (c), 0, 0, 0)

__device__ __forceinline__ short f2bf(float f) {
  return __builtin_bit_cast(short, __float2bfloat16(f));
}
__device__ __forceinline__ float bf2f(short b) {
  return __builtin_bit_cast(float, ((unsigned)(unsigned short)b) << 16);
}

// LDS-only barrier (null vs __syncthreads per round-5 A/B, kept: strictly no worse)
__device__ __forceinline__ void sync_lds() {
  asm volatile("s_waitcnt lgkmcnt(0)" ::: "memory");
  __builtin_amdgcn_s_barrier();
  asm volatile("" ::: "memory");
}

constexpr int L = 2048, D = 64, KT = 64, NT = L / KT;   // 32 k-tiles
constexpr int NHEAD = 64;                                // B*H
// softmax in exp2 domain: exp(s/T) = exp2(s * 0.125*log2(e))
constexpr float QSCALE = 0.18033688011112042f;
constexpr size_t WS_NEED = (size_t)3 * NHEAD * L * D * sizeof(short);  // ~50.3 MB

// ============ prep: f32 -> bf16 (Q scaled; V transposed per head) ============
__global__ __launch_bounds__(256)
void sdpa_prep(const float* __restrict__ Q, const float* __restrict__ K,
               const float* __restrict__ V,
               short* __restrict__ Qb, short* __restrict__ Kb,
               short* __restrict__ Vtb)
{
  __shared__ short Tl[64 * 72];          // pad 72 -> conflict-lite, b128-aligned rows
  const int t = threadIdx.x;
  const int head = blockIdx.x >> 5, kt = blockIdx.x & 31;
  const long base = (long)head * L * D + (long)kt * 64 * D;   // 4096 elems

  // Q, K: straight cvt, 16 elems/thread, fully coalesced
  {
    const float* qp = Q + base + t * 16;
    short*       qo = Qb + base + t * 16;
    bf16x8 y0, y1;
    #pragma unroll
    for (int j = 0; j < 8; ++j) {
      y0[j] = f2bf(qp[j]     * QSCALE);
      y1[j] = f2bf(qp[8 + j] * QSCALE);
    }
    *(bf16x8*)qo = y0; *(bf16x8*)(qo + 8) = y1;
  }
  {
    const float* kp = K + base + t * 16;
    short*       ko = Kb + base + t * 16;
    bf16x8 y0, y1;
    #pragma unroll
    for (int j = 0; j < 8; ++j) { y0[j] = f2bf(kp[j]); y1[j] = f2bf(kp[8 + j]); }
    *(bf16x8*)ko = y0; *(bf16x8*)(ko + 8) = y1;
  }
  // V: 64x64 transpose via LDS (4x4 in-register blocks)
  {
    const int kr0 = (t >> 4) * 4, d0 = (t & 15) * 4;
    const float* vp = V + base;
    f32x4 r[4];
    #pragma unroll
    for (int i = 0; i < 4; ++i) r[i] = *(const f32x4*)(vp + (kr0 + i) * D + d0);
    #pragma unroll
    for (int j = 0; j < 4; ++j) {
      bf16x4 y;
      #pragma unroll
      for (int i = 0; i < 4; ++i) y[i] = f2bf(r[i][j]);
      *(bf16x4*)(&Tl[(d0 + j) * 72 + kr0]) = y;
    }
  }
  __syncthreads();
  {
    const int d = t >> 2, k0 = (t & 3) * 16;
    bf16x8 a = *(const bf16x8*)(&Tl[d * 72 + k0]);
    bf16x8 b = *(const bf16x8*)(&Tl[d * 72 + k0 + 8]);
    short* vo = Vtb + (long)head * D * L + (long)d * L + kt * 64 + k0;
    *(bf16x8*)vo = a; *(bf16x8*)(vo + 8) = b;
  }
}

// ============ main: bf16-staged fused SDPA ============
__global__ __launch_bounds__(256, 4)
void sdpa_main(const short* __restrict__ Qb, const short* __restrict__ Kb,
               const short* __restrict__ Vtb, float* __restrict__ out,
               float* __restrict__ attn)
{
  __shared__ short Klds[2][KT * D];     // [buf][kr][d^sw]
  __shared__ short Vlds[2][D * KT];     // [buf][d][kr^sw]  (V^T)
  __shared__ short Plds[4][16 * KT];    // per-wave [q][k^sw]

  const int t = threadIdx.x, lane = t & 63, w = t >> 6;
  const int qr = lane & 15, g = lane >> 4;

  // bijective XCD swizzle (2048 % 8 == 0): all 32 blocks of a head on one XCD
  const int bid = blockIdx.x;
  const int wid = ((bid & 7) << 8) | (bid >> 3);
  const int head = wid >> 5, qt = wid & 31;
  const long hoff = (long)head * L * D;
  const int qrow0 = qt * 64 + w * 16;

  // Q fragments: direct bf16 loads (scale pre-folded)
  bf16x8 qfrag[2];
  {
    const short* qbp = Qb + hoff + (long)(qrow0 + qr) * D + g * 8;
    qfrag[0] = *(const bf16x8*)qbp;
    qfrag[1] = *(const bf16x8*)(qbp + 32);
  }

  const short* Kbase = Kb + hoff;
  const short* Vbase = Vtb + (long)head * D * L;

  bf16x8 kreg[2], vreg[2];
  const int krow = t >> 2, kd0 = (t & 3) * 16;   // K stage coords
  const int vd   = t >> 2, vk0 = (t & 3) * 16;   // V stage coords

  auto loadK = [&](int kt) {
    const short* kp = Kbase + (long)(kt * KT + krow) * D + kd0;
    kreg[0] = *(const bf16x8*)kp;
    kreg[1] = *(const bf16x8*)(kp + 8);
  };
  auto writeK = [&](int buf) {
    const int sw = (krow & 7) << 3;
    *(bf16x8*)(&Klds[buf][krow * 64 + (kd0 ^ sw)])       = kreg[0];
    *(bf16x8*)(&Klds[buf][krow * 64 + ((kd0 + 8) ^ sw)]) = kreg[1];
  };
  auto loadV = [&](int kt) {
    const short* vp = Vbase + (long)vd * L + kt * KT + vk0;
    vreg[0] = *(const bf16x8*)vp;
    vreg[1] = *(const bf16x8*)(vp + 8);
  };
  auto writeV = [&](int buf) {
    const int sw = (vd & 7) << 3;
    *(bf16x8*)(&Vlds[buf][vd * 64 + (vk0 ^ sw)])       = vreg[0];
    *(bf16x8*)(&Vlds[buf][vd * 64 + ((vk0 + 8) ^ sw)]) = vreg[1];
  };

  auto computeS = [&](int buf, f32x4 s[4]) {
    #pragma unroll
    for (int f = 0; f < 4; ++f) {
      s[f] = (f32x4){0.f, 0.f, 0.f, 0.f};
      int kr = f * 16 + qr;
      #pragma unroll
      for (int c = 0; c < 2; ++c) {
        int d0c = g * 8 + 32 * c;
        bf16x8 a = *(const bf16x8*)(&Klds[buf][kr * 64 + (d0c ^ ((kr & 7) << 3))]);
        s[f] = MFMA16(a, qfrag[c], s[f]);
      }
    }
  };

  // ---- pass 1: row sums ----
  loadK(0); writeK(0);
  sync_lds();
  float rsum = 0.f;
  for (int kt = 0; kt < NT; ++kt) {
    const int cur = kt & 1;
    if (kt + 1 < NT) loadK(kt + 1);
    f32x4 s[4];
    computeS(cur, s);
    #pragma unroll
    for (int f = 0; f < 4; ++f)
      #pragma unroll
      for (int r = 0; r < 4; ++r)
        rsum += __builtin_amdgcn_exp2f(s[f][r]);
    if (kt + 1 < NT) writeK(cur ^ 1);
    sync_lds();
  }
  rsum += __shfl_xor(rsum, 16);
  rsum += __shfl_xor(rsum, 32);
  const float rinv = 1.f / rsum;

  // ---- pass 2: attn + O ----
  f32x4 o[4] = {{0.f,0.f,0.f,0.f},{0.f,0.f,0.f,0.f},{0.f,0.f,0.f,0.f},{0.f,0.f,0.f,0.f}};
  // lane's attn row pointer (q = qrow0+qr fixed per lane)
  float* ap_row = attn + (long)head * L * L + (long)(qrow0 + qr) * L;

  loadK(0); loadV(0);
  writeK(0); writeV(0);
  sync_lds();

  for (int kt = 0; kt < NT; ++kt) {
    const int cur = kt & 1;
    if (kt + 1 < NT) { loadK(kt + 1); loadV(kt + 1); }

    f32x4 s[4];
    computeS(cur, s);

    // P = exp2(s)*rinv: f32 -> attn directly; bf16 -> Plds for PV
    #pragma unroll
    for (int f = 0; f < 4; ++f) {
      f32x4 pf;
      #pragma unroll
      for (int r = 0; r < 4; ++r)
        pf[r] = __builtin_amdgcn_exp2f(s[f][r]) * rinv;
      // direct attn store: k = kt*64 + f*16 + g*4 + r (4 consecutive k)
      *(f32x4*)(ap_row + kt * KT + f * 16 + g * 4) = pf;
      bf16x4 p;
      #pragma unroll
      for (int r = 0; r < 4; ++r) p[r] = f2bf(pf[r]);
      int k0 = f * 16 + g * 4;
      *(bf16x4*)(&Plds[w][qr * 64 + (k0 ^ ((qr & 7) << 3))]) = p;
    }
    __builtin_amdgcn_wave_barrier();   // order P writes before PV reads (wave-private)

    // PV: O(16q x 64d) += P(16x64) * V(64x64)
    #pragma unroll
    for (int kc = 0; kc < 2; ++kc) {
      int k0 = kc * 32 + g * 8;
      bf16x8 pa = *(const bf16x8*)(&Plds[w][qr * 64 + (k0 ^ ((qr & 7) << 3))]);
      #pragma unroll
      for (int fr = 0; fr < 4; ++fr) {
        int d = fr * 16 + qr;
        bf16x8 vb = *(const bf16x8*)(&Vlds[cur][d * 64 + (k0 ^ ((d & 7) << 3))]);
        o[fr] = MFMA16(pa, vb, o[fr]);
      }
    }

    if (kt + 1 < NT) { writeK(cur ^ 1); writeV(cur ^ 1); }
    sync_lds();
  }

  float* op = out + hoff + (long)qrow0 * D;
  #pragma unroll
  for (int fr = 0; fr < 4; ++fr)
    #pragma unroll
    for (int r = 0; r < 4; ++r) {
      int qq = g * 4 + r;
      op[(long)qq * D + fr * 16 + qr] = o[fr][r];
    }
}

// ============ fallback (round-5 proven kernel, f32-staged) ============
__global__ __launch_bounds__(256, 4)
void sdpa_fused(const float* __restrict__ Q, const float* __restrict__ K,
                const float* __restrict__ V, float* __restrict__ out,
                float* __restrict__ attn)
{
  __shared__ short Klds[2][KT * D];
  __shared__ short Vlds[2][D * KT];
  __shared__ short Plds[4][16 * KT];

  const int t = threadIdx.x, lane = t & 63, w = t >> 6;
  const int qr = lane & 15, g = lane >> 4;
  const int head = blockIdx.x >> 5, qt = blockIdx.x & 31;
  const long hoff = (long)head * L * D;
  const int qrow0 = qt * 64 + w * 16;

  bf16x8 qfrag[2];
  {
    const float* qp = Q + hoff + (long)(qrow0 + qr) * D + g * 8;
    #pragma unroll
    for (int c = 0; c < 2; ++c)
      #pragma unroll
      for (int j = 0; j < 8; ++j)
        qfrag[c][j] = f2bf(qp[32 * c + j] * QSCALE);
  }

  const float* Kbase = Q == nullptr ? nullptr : K + hoff;
  const float* Vbase = V + hoff;
  f32x4 kreg[4], vreg[4];

  auto loadK = [&](int kt) {
    const float* kp = Kbase + (long)kt * KT * D;
    #pragma unroll
    for (int c = 0; c < 4; ++c)
      kreg[c] = *(const f32x4*)(kp + (t + 256 * c) * 4);
  };
  auto writeK = [&](int buf) {
    #pragma unroll
    for (int c = 0; c < 4; ++c) {
      int f = t + 256 * c;
      int kr = f >> 4, col = (f & 15) * 4;
      bf16x4 y;
      #pragma unroll
      for (int i = 0; i < 4; ++i) y[i] = f2bf(kreg[c][i]);
      *(bf16x4*)(&Klds[buf][kr * 64 + (col ^ ((kr & 7) << 3))]) = y;
    }
  };
  auto loadV = [&](int kt) {
    const float* vp = Vbase + (long)kt * KT * D;
    int kr0 = (t >> 4) * 4, d0 = (t & 15) * 4;
    #pragma unroll
    for (int i = 0; i < 4; ++i)
      vreg[i] = *(const f32x4*)(vp + (kr0 + i) * D + d0);
  };
  auto writeV = [&](int buf) {
    int kr0 = (t >> 4) * 4, d0 = (t & 15) * 4;
    #pragma unroll
    for (int j = 0; j < 4; ++j) {
      bf16x4 y;
      #pragma unroll
      for (int i = 0; i < 4; ++i) y[i] = f2bf(vreg[i][j]);
      int d = d0 + j;
      *(bf16x4*)(&Vlds[buf][d * 64 + (kr0 ^ ((d & 7) << 3))]) = y;
    }
  };
  auto computeS = [&](int buf, f32x4 s[4]) {
    #pragma unroll
    for (int f = 0; f < 4; ++f) {
      s[f] = (f32x4){0.f, 0.f, 0.f, 0.f};
      int kr = f * 16 + qr;
      #pragma unroll
      for (int c = 0; c < 2; ++c) {
        int d0c = g * 8 + 32 * c;
        bf16x8 a = *(const bf16x8*)(&Klds[buf][kr * 64 + (d0c ^ ((kr & 7) << 3))]);
        s[f] = MFMA16(a, qfrag[c], s[f]);
      }
    }
  };

  loadK(0); writeK(0);
  sync_lds();
  float rsum = 0.f;
  for (int kt = 0; kt < NT; ++kt) {
    const int cur = kt & 1;
    if (kt + 1 < NT) loadK(kt + 1);
    f32x4 s[4];
    computeS(cur, s);
    #pragma unroll
    for (int f = 0; f < 4; ++f)
      #pragma unroll
      for (int r = 0; r < 4; ++r)
        rsum += __builtin_amdgcn_exp2f(s[f][r]);
    if (kt + 1 < NT) writeK(cur ^ 1);
    sync_lds();
  }
  rsum += __shfl_xor(rsum, 16);
  rsum += __shfl_xor(rsum, 32);
  const float rinv = 1.f / rsum;

  f32x4 o[4] = {{0.f,0.f,0.f,0.f},{0.f,0.f,0.f,0.f},{0.f,0.f,0.f,0.f},{0.f,0.f,0.f,0.f}};
  float* ap_base = attn + (long)head * L * L + (long)qrow0 * L;

  loadK(0); loadV(0);
  writeK(0); writeV(0);
  sync_lds();

  for (int kt = 0; kt < NT; ++kt) {
    const int cur = kt & 1;
    if (kt + 1 < NT) { loadK(kt + 1); loadV(kt + 1); }

    f32x4 s[4];
    computeS(cur, s);

    #pragma unroll
    for (int f = 0; f < 4; ++f) {
      bf16x4 p;
      #pragma unroll
      for (int r = 0; r < 4; ++r)
        p[r] = f2bf(__builtin_amdgcn_exp2f(s[f][r]) * rinv);
      int k0 = f * 16 + g * 4;
      *(bf16x4*)(&Plds[w][qr * 64 + (k0 ^ ((qr & 7) << 3))]) = p;
    }
    __builtin_amdgcn_wave_barrier();

    float* ap = ap_base + (long)kt * KT;
    #pragma unroll
    for (int i = 0; i < 4; ++i) {
      int r = 4 * i + g, col = 4 * qr;
      bf16x4 pb = *(const bf16x4*)(&Plds[w][r * 64 + (col ^ ((r & 7) << 3))]);
      f32x4 pf;
      #pragma unroll
      for (int j = 0; j < 4; ++j) pf[j] = bf2f(pb[j]);
      *(f32x4*)(ap + (long)r * L + col) = pf;
    }

    #pragma unroll
    for (int kc = 0; kc < 2; ++kc) {
      int k0 = kc * 32 + g * 8;
      bf16x8 pa = *(const bf16x8*)(&Plds[w][qr * 64 + (k0 ^ ((qr & 7) << 3))]);
      #pragma unroll
      for (int fr = 0; fr < 4; ++fr) {
        int d = fr * 16 + qr;
        bf16x8 vb = *(const bf16x8*)(&Vlds[cur][d * 64 + (k0 ^ ((d & 7) << 3))]);
        o[fr] = MFMA16(pa, vb, o[fr]);
      }
    }

    if (kt + 1 < NT) { writeK(cur ^ 1); writeV(cur ^ 1); }
    sync_lds();
  }

  float* op = out + hoff + (long)qrow0 * D;
  #pragma unroll
  for (int fr = 0; fr < 4; ++fr)
    #pragma unroll
    for (int r = 0; r < 4; ++r) {
      int qq = g * 4 + r;
      op[(long)qq * D + fr * 16 + qr] = o[fr][r];
    }
}

extern "C" void kernel_launch(void* const* d_in, const int* in_sizes, int n_in,
                              void* d_out, int out_size, void* d_ws, size_t ws_size,
                              hipStream_t stream) {
  const float* q = (const float*)d_in[0];
  const float* k = (const float*)d_in[1];
  const float* v = (const float*)d_in[2];
  float* out  = (float*)d_out;                          // (B,H,L,D)
  float* attn = (float*)d_out + (size_t)NHEAD * L * D;  // (B,H,L,L)

  dim3 grid(NHEAD * NT);   // 2048
  dim3 block(256);

  if (ws_size >= WS_NEED) {
    short* Qb  = (short*)d_ws;
    short* Kb  = Qb + (size_t)NHEAD * L * D;
    short* Vtb = Kb + (size_t)NHEAD * L * D;
    hipLaunchKernelGGL(sdpa_prep, grid, block, 0, stream, q, k, v, Qb, Kb, Vtb);
    hipLaunchKernelGGL(sdpa_main, grid, block, 0, stream, Qb, Kb, Vtb, out, attn);
  } else {
    hipLaunchKernelGGL(sdpa_fused, grid, block, 0, stream, q, k, v, out, attn);
  }
}

// Round 7
// 352.113 us; speedup vs baseline: 1.4648x; 1.0996x over previous
//
#include <hip/hip_runtime.h>
#include <hip/hip_bf16.h>

typedef __attribute__((ext_vector_type(4))) float  f32x4;
typedef __attribute__((ext_vector_type(8))) short  bf16x8;
typedef __attribute__((ext_vector_type(4))) short  bf16x4;

#define MFMA16(a, b, c) __builtin_amdgcn_mfma_f32_16x16x32_bf16((a), (b), (c), 0, 0, 0)

__device__ __forceinline__ short f2bf(float f) {
  return __builtin_bit_cast(short, __float2bfloat16(f));
}
__device__ __forceinline__ float bf2f(short b) {
  return __builtin_bit_cast(float, ((unsigned)(unsigned short)b) << 16);
}

__device__ __forceinline__ void sync_lds() {
  asm volatile("s_waitcnt lgkmcnt(0)" ::: "memory");
  __builtin_amdgcn_s_barrier();
  asm volatile("" ::: "memory");
}

constexpr int L = 2048, D = 64, KT = 64, NT = L / KT;   // 32 k-tiles
constexpr int NHEAD = 64;
constexpr int QB = 128, NQT = L / QB;                    // 16 q-tiles -> grid 1024
constexpr float QSCALE = 0.18033688011112042f;           // 0.125*log2(e)
constexpr size_t WS_NEED = (size_t)3 * NHEAD * L * D * sizeof(short);

// ============ prep: f32 -> bf16 (Q scaled; V transposed per head) ============
__global__ __launch_bounds__(256)
void sdpa_prep(const float* __restrict__ Q, const float* __restrict__ K,
               const float* __restrict__ V,
               short* __restrict__ Qb, short* __restrict__ Kb,
               short* __restrict__ Vtb)
{
  __shared__ short Tl[64 * 72];
  const int t = threadIdx.x;
  const int head = blockIdx.x >> 5, kt = blockIdx.x & 31;
  const long base = (long)head * L * D + (long)kt * 64 * D;

  {
    const float* qp = Q + base + t * 16;
    short*       qo = Qb + base + t * 16;
    bf16x8 y0, y1;
    #pragma unroll
    for (int j = 0; j < 8; ++j) {
      y0[j] = f2bf(qp[j]     * QSCALE);
      y1[j] = f2bf(qp[8 + j] * QSCALE);
    }
    *(bf16x8*)qo = y0; *(bf16x8*)(qo + 8) = y1;
  }
  {
    const float* kp = K + base + t * 16;
    short*       ko = Kb + base + t * 16;
    bf16x8 y0, y1;
    #pragma unroll
    for (int j = 0; j < 8; ++j) { y0[j] = f2bf(kp[j]); y1[j] = f2bf(kp[8 + j]); }
    *(bf16x8*)ko = y0; *(bf16x8*)(ko + 8) = y1;
  }
  {
    const int kr0 = (t >> 4) * 4, d0 = (t & 15) * 4;
    const float* vp = V + base;
    f32x4 r[4];
    #pragma unroll
    for (int i = 0; i < 4; ++i) r[i] = *(const f32x4*)(vp + (kr0 + i) * D + d0);
    #pragma unroll
    for (int j = 0; j < 4; ++j) {
      bf16x4 y;
      #pragma unroll
      for (int i = 0; i < 4; ++i) y[i] = f2bf(r[i][j]);
      *(bf16x4*)(&Tl[(d0 + j) * 72 + kr0]) = y;
    }
  }
  __syncthreads();
  {
    const int d = t >> 2, k0 = (t & 3) * 16;
    bf16x8 a = *(const bf16x8*)(&Tl[d * 72 + k0]);
    bf16x8 b = *(const bf16x8*)(&Tl[d * 72 + k0 + 8]);
    short* vo = Vtb + (long)head * D * L + (long)d * L + kt * 64 + k0;
    *(bf16x8*)vo = a; *(bf16x8*)(vo + 8) = b;
  }
}

// ============ main: 32 q-rows/wave, K-frag reuse across q-halves ============
__global__ __launch_bounds__(256, 4)
void sdpa_main(const short* __restrict__ Qb, const short* __restrict__ Kb,
               const short* __restrict__ Vtb, float* __restrict__ out,
               float* __restrict__ attn)
{
  __shared__ short Klds[2][KT * D];     // 16 KB
  __shared__ short Vlds[2][D * KT];     // 16 KB
  __shared__ short Plds[4][16 * KT];    // 8 KB (per-wave, reused per q-half)

  const int t = threadIdx.x, lane = t & 63, w = t >> 6;
  const int qr = lane & 15, g = lane >> 4;

  // bijective XCD swizzle (1024 % 8 == 0): all 16 blocks of a head on one XCD
  const int bid = blockIdx.x;
  const int wid = ((bid & 7) << 7) | (bid >> 3);
  const int head = wid >> 4, qt = wid & 15;
  const long hoff = (long)head * L * D;
  const int qrow0 = qt * QB + w * 32;   // wave owns 32 q-rows (2 halves of 16)

  bf16x8 qfrag[2][2];                   // [half][d-chunk]
  #pragma unroll
  for (int h = 0; h < 2; ++h) {
    const short* qbp = Qb + hoff + (long)(qrow0 + 16 * h + qr) * D + g * 8;
    qfrag[h][0] = *(const bf16x8*)qbp;
    qfrag[h][1] = *(const bf16x8*)(qbp + 32);
  }

  const short* Kbase = Kb + hoff;
  const short* Vbase = Vtb + (long)head * D * L;

  bf16x8 kreg[2], vreg[2];
  const int krow = t >> 2, kd0 = (t & 3) * 16;

  auto loadK = [&](int kt) {
    const short* kp = Kbase + (long)(kt * KT + krow) * D + kd0;
    kreg[0] = *(const bf16x8*)kp;
    kreg[1] = *(const bf16x8*)(kp + 8);
  };
  auto writeK = [&](int buf) {
    const int sw = (krow & 7) << 3;
    *(bf16x8*)(&Klds[buf][krow * 64 + (kd0 ^ sw)])       = kreg[0];
    *(bf16x8*)(&Klds[buf][krow * 64 + ((kd0 + 8) ^ sw)]) = kreg[1];
  };
  auto loadV = [&](int kt) {
    const short* vp = Vbase + (long)krow * L + kt * KT + kd0;
    vreg[0] = *(const bf16x8*)vp;
    vreg[1] = *(const bf16x8*)(vp + 8);
  };
  auto writeV = [&](int buf) {
    const int sw = (krow & 7) << 3;
    *(bf16x8*)(&Vlds[buf][krow * 64 + (kd0 ^ sw)])       = vreg[0];
    *(bf16x8*)(&Vlds[buf][krow * 64 + ((kd0 + 8) ^ sw)]) = vreg[1];
  };

  // S for BOTH q-halves with one K-frag load (A-operand shared)
  auto computeS2 = [&](int buf, f32x4 s0[4], f32x4 s1[4]) {
    #pragma unroll
    for (int f = 0; f < 4; ++f) {
      s0[f] = (f32x4){0.f, 0.f, 0.f, 0.f};
      s1[f] = (f32x4){0.f, 0.f, 0.f, 0.f};
      int kr = f * 16 + qr;
      #pragma unroll
      for (int c = 0; c < 2; ++c) {
        int d0c = g * 8 + 32 * c;
        bf16x8 a = *(const bf16x8*)(&Klds[buf][kr * 64 + (d0c ^ ((kr & 7) << 3))]);
        s0[f] = MFMA16(a, qfrag[0][c], s0[f]);
        s1[f] = MFMA16(a, qfrag[1][c], s1[f]);
      }
    }
  };

  // ---- pass 1: row sums ----
  loadK(0); writeK(0);
  sync_lds();
  float rsum0 = 0.f, rsum1 = 0.f;
  for (int kt = 0; kt < NT; ++kt) {
    const int cur = kt & 1;
    if (kt + 1 < NT) loadK(kt + 1);
    f32x4 s0[4], s1[4];
    computeS2(cur, s0, s1);
    #pragma unroll
    for (int f = 0; f < 4; ++f)
      #pragma unroll
      for (int r = 0; r < 4; ++r) {
        rsum0 += __builtin_amdgcn_exp2f(s0[f][r]);
        rsum1 += __builtin_amdgcn_exp2f(s1[f][r]);
      }
    if (kt + 1 < NT) writeK(cur ^ 1);
    sync_lds();
  }
  rsum0 += __shfl_xor(rsum0, 16); rsum0 += __shfl_xor(rsum0, 32);
  rsum1 += __shfl_xor(rsum1, 16); rsum1 += __shfl_xor(rsum1, 32);
  const float rinv0 = 1.f / rsum0;
  const float rinv1 = 1.f / rsum1;

  // ---- pass 2: attn + O ----
  f32x4 o0[4] = {{0.f,0.f,0.f,0.f},{0.f,0.f,0.f,0.f},{0.f,0.f,0.f,0.f},{0.f,0.f,0.f,0.f}};
  f32x4 o1[4] = {{0.f,0.f,0.f,0.f},{0.f,0.f,0.f,0.f},{0.f,0.f,0.f,0.f},{0.f,0.f,0.f,0.f}};
  float* ap0 = attn + (long)head * L * L + (long)(qrow0 + qr) * L;
  float* ap1 = ap0 + 16 * L;

  // one q-half: attn write (direct f32), P->Plds, PV accumulate
  auto doHalf = [&](f32x4 s[4], float rinv, float* ap, f32x4 o[4], int cur, int kt) {
    #pragma unroll
    for (int f = 0; f < 4; ++f) {
      f32x4 pf;
      #pragma unroll
      for (int r = 0; r < 4; ++r)
        pf[r] = __builtin_amdgcn_exp2f(s[f][r]) * rinv;
      *(f32x4*)(ap + kt * KT + f * 16 + g * 4) = pf;
      bf16x4 p;
      #pragma unroll
      for (int r = 0; r < 4; ++r) p[r] = f2bf(pf[r]);
      int k0 = f * 16 + g * 4;
      *(bf16x4*)(&Plds[w][qr * 64 + (k0 ^ ((qr & 7) << 3))]) = p;
    }
    __builtin_amdgcn_wave_barrier();   // P writes before PV reads (wave-private)
    #pragma unroll
    for (int kc = 0; kc < 2; ++kc) {
      int k0 = kc * 32 + g * 8;
      bf16x8 pa = *(const bf16x8*)(&Plds[w][qr * 64 + (k0 ^ ((qr & 7) << 3))]);
      #pragma unroll
      for (int fr = 0; fr < 4; ++fr) {
        int d = fr * 16 + qr;
        bf16x8 vb = *(const bf16x8*)(&Vlds[cur][d * 64 + (k0 ^ ((d & 7) << 3))]);
        o[fr] = MFMA16(pa, vb, o[fr]);
      }
    }
    __builtin_amdgcn_wave_barrier();   // PV reads before next half's P writes (WAR)
  };

  loadK(0); loadV(0);
  writeK(0); writeV(0);
  sync_lds();

  for (int kt = 0; kt < NT; ++kt) {
    const int cur = kt & 1;
    if (kt + 1 < NT) { loadK(kt + 1); loadV(kt + 1); }

    f32x4 s0[4], s1[4];
    computeS2(cur, s0, s1);

    doHalf(s0, rinv0, ap0, o0, cur, kt);
    doHalf(s1, rinv1, ap1, o1, cur, kt);

    if (kt + 1 < NT) { writeK(cur ^ 1); writeV(cur ^ 1); }
    sync_lds();
  }

  float* op = out + hoff + (long)qrow0 * D;
  #pragma unroll
  for (int fr = 0; fr < 4; ++fr)
    #pragma unroll
    for (int r = 0; r < 4; ++r) {
      op[(long)(g * 4 + r) * D + fr * 16 + qr]      = o0[fr][r];
      op[(long)(16 + g * 4 + r) * D + fr * 16 + qr] = o1[fr][r];
    }
}

// ============ fallback (round-5 proven kernel, f32-staged) ============
__global__ __launch_bounds__(256, 4)
void sdpa_fused(const float* __restrict__ Q, const float* __restrict__ K,
                const float* __restrict__ V, float* __restrict__ out,
                float* __restrict__ attn)
{
  __shared__ short Klds[2][KT * D];
  __shared__ short Vlds[2][D * KT];
  __shared__ short Plds[4][16 * KT];

  const int t = threadIdx.x, lane = t & 63, w = t >> 6;
  const int qr = lane & 15, g = lane >> 4;
  const int head = blockIdx.x >> 5, qt = blockIdx.x & 31;
  const long hoff = (long)head * L * D;
  const int qrow0 = qt * 64 + w * 16;

  bf16x8 qfrag[2];
  {
    const float* qp = Q + hoff + (long)(qrow0 + qr) * D + g * 8;
    #pragma unroll
    for (int c = 0; c < 2; ++c)
      #pragma unroll
      for (int j = 0; j < 8; ++j)
        qfrag[c][j] = f2bf(qp[32 * c + j] * QSCALE);
  }

  const float* Kbase = K + hoff;
  const float* Vbase = V + hoff;
  f32x4 kreg[4], vreg[4];

  auto loadK = [&](int kt) {
    const float* kp = Kbase + (long)kt * KT * D;
    #pragma unroll
    for (int c = 0; c < 4; ++c)
      kreg[c] = *(const f32x4*)(kp + (t + 256 * c) * 4);
  };
  auto writeK = [&](int buf) {
    #pragma unroll
    for (int c = 0; c < 4; ++c) {
      int f = t + 256 * c;
      int kr = f >> 4, col = (f & 15) * 4;
      bf16x4 y;
      #pragma unroll
      for (int i = 0; i < 4; ++i) y[i] = f2bf(kreg[c][i]);
      *(bf16x4*)(&Klds[buf][kr * 64 + (col ^ ((kr & 7) << 3))]) = y;
    }
  };
  auto loadV = [&](int kt) {
    const float* vp = Vbase + (long)kt * KT * D;
    int kr0 = (t >> 4) * 4, d0 = (t & 15) * 4;
    #pragma unroll
    for (int i = 0; i < 4; ++i)
      vreg[i] = *(const f32x4*)(vp + (kr0 + i) * D + d0);
  };
  auto writeV = [&](int buf) {
    int kr0 = (t >> 4) * 4, d0 = (t & 15) * 4;
    #pragma unroll
    for (int j = 0; j < 4; ++j) {
      bf16x4 y;
      #pragma unroll
      for (int i = 0; i < 4; ++i) y[i] = f2bf(vreg[i][j]);
      int d = d0 + j;
      *(bf16x4*)(&Vlds[buf][d * 64 + (kr0 ^ ((d & 7) << 3))]) = y;
    }
  };
  auto computeS = [&](int buf, f32x4 s[4]) {
    #pragma unroll
    for (int f = 0; f < 4; ++f) {
      s[f] = (f32x4){0.f, 0.f, 0.f, 0.f};
      int kr = f * 16 + qr;
      #pragma unroll
      for (int c = 0; c < 2; ++c) {
        int d0c = g * 8 + 32 * c;
        bf16x8 a = *(const bf16x8*)(&Klds[buf][kr * 64 + (d0c ^ ((kr & 7) << 3))]);
        s[f] = MFMA16(a, qfrag[c], s[f]);
      }
    }
  };

  loadK(0); writeK(0);
  sync_lds();
  float rsum = 0.f;
  for (int kt = 0; kt < NT; ++kt) {
    const int cur = kt & 1;
    if (kt + 1 < NT) loadK(kt + 1);
    f32x4 s[4];
    computeS(cur, s);
    #pragma unroll
    for (int f = 0; f < 4; ++f)
      #pragma unroll
      for (int r = 0; r < 4; ++r)
        rsum += __builtin_amdgcn_exp2f(s[f][r]);
    if (kt + 1 < NT) writeK(cur ^ 1);
    sync_lds();
  }
  rsum += __shfl_xor(rsum, 16);
  rsum += __shfl_xor(rsum, 32);
  const float rinv = 1.f / rsum;

  f32x4 o[4] = {{0.f,0.f,0.f,0.f},{0.f,0.f,0.f,0.f},{0.f,0.f,0.f,0.f},{0.f,0.f,0.f,0.f}};
  float* ap_base = attn + (long)head * L * L + (long)qrow0 * L;

  loadK(0); loadV(0);
  writeK(0); writeV(0);
  sync_lds();

  for (int kt = 0; kt < NT; ++kt) {
    const int cur = kt & 1;
    if (kt + 1 < NT) { loadK(kt + 1); loadV(kt + 1); }

    f32x4 s[4];
    computeS(cur, s);

    #pragma unroll
    for (int f = 0; f < 4; ++f) {
      bf16x4 p;
      #pragma unroll
      for (int r = 0; r < 4; ++r)
        p[r] = f2bf(__builtin_amdgcn_exp2f(s[f][r]) * rinv);
      int k0 = f * 16 + g * 4;
      *(bf16x4*)(&Plds[w][qr * 64 + (k0 ^ ((qr & 7) << 3))]) = p;
    }
    __builtin_amdgcn_wave_barrier();

    float* ap = ap_base + (long)kt * KT;
    #pragma unroll
    for (int i = 0; i < 4; ++i) {
      int r = 4 * i + g, col = 4 * qr;
      bf16x4 pb = *(const bf16x4*)(&Plds[w][r * 64 + (col ^ ((r & 7) << 3))]);
      f32x4 pf;
      #pragma unroll
      for (int j = 0; j < 4; ++j) pf[j] = bf2f(pb[j]);
      *(f32x4*)(ap + (long)r * L + col) = pf;
    }

    #pragma unroll
    for (int kc = 0; kc < 2; ++kc) {
      int k0 = kc * 32 + g * 8;
      bf16x8 pa = *(const bf16x8*)(&Plds[w][qr * 64 + (k0 ^ ((qr & 7) << 3))]);
      #pragma unroll
      for (int fr = 0; fr < 4; ++fr) {
        int d = fr * 16 + qr;
        bf16x8 vb = *(const bf16x8*)(&Vlds[cur][d * 64 + (k0 ^ ((d & 7) << 3))]);
        o[fr] = MFMA16(pa, vb, o[fr]);
      }
    }

    if (kt + 1 < NT) { writeK(cur ^ 1); writeV(cur ^ 1); }
    sync_lds();
  }

  float* op = out + hoff + (long)qrow0 * D;
  #pragma unroll
  for (int fr = 0; fr < 4; ++fr)
    #pragma unroll
    for (int r = 0; r < 4; ++r) {
      int qq = g * 4 + r;
      op[(long)qq * D + fr * 16 + qr] = o[fr][r];
    }
}

extern "C" void kernel_launch(void* const* d_in, const int* in_sizes, int n_in,
                              void* d_out, int out_size, void* d_ws, size_t ws_size,
                              hipStream_t stream) {
  const float* q = (const float*)d_in[0];
  const float* k = (const float*)d_in[1];
  const float* v = (const float*)d_in[2];
  float* out  = (float*)d_out;                          // (B,H,L,D)
  float* attn = (float*)d_out + (size_t)NHEAD * L * D;  // (B,H,L,L)

  dim3 block(256);

  if (ws_size >= WS_NEED) {
    short* Qb  = (short*)d_ws;
    short* Kb  = Qb + (size_t)NHEAD * L * D;
    short* Vtb = Kb + (size_t)NHEAD * L * D;
    hipLaunchKernelGGL(sdpa_prep, dim3(NHEAD * NT), block, 0, stream, q, k, v, Qb, Kb, Vtb);
    hipLaunchKernelGGL(sdpa_main, dim3(NHEAD * NQT), block, 0, stream, Qb, Kb, Vtb, out, attn);
  } else {
    hipLaunchKernelGGL(sdpa_fused, dim3(NHEAD * NT), block, 0, stream, q, k, v, out, attn);
  }
}